// Round 2
// baseline (1027.688 us; speedup 1.0000x reference)
//
#include <hip/hip_runtime.h>
#include <hip/hip_bf16.h>
#include <stdint.h>

// Problem constants: N=262144 rows, C=256 channels, K=256 codes.
#define CCH 256
#define KK  256
#define GROUPS 16           // channel groups
#define CPG    16           // channels per group (LDS codebook slice = 16KB)
#define ROWS_PER_BLOCK 512  // N % 512 == 0

typedef int   v4i __attribute__((ext_vector_type(4)));
typedef float v4f __attribute__((ext_vector_type(4)));

// ---------------------------------------------------------------------------
// Pass 1: compress white_table int32 -> uint8 (values are codes in [0,256)).
// ---------------------------------------------------------------------------
__global__ __launch_bounds__(256) void compress_table_kernel(
    const int4* __restrict__ t, uchar4* __restrict__ o, int n4) {
  int i = blockIdx.x * 256 + threadIdx.x;
  if (i < n4) {
    int4 v = t[i];
    o[i] = make_uchar4((unsigned char)v.x, (unsigned char)v.y,
                       (unsigned char)v.z, (unsigned char)v.w);
  }
}

// ---------------------------------------------------------------------------
// Pass 2: fused double-gather.
//   g = blockIdx.x & 15 -> 16-channel group. Consecutive blockIdx round-robin
//   across 8 XCDs, so each XCD L2 hot-caches 2 groups x 1MB u8 table slice.
//   Thread layout: q = tid&1 -> channel octet (8 consecutive channels, two
//   int4/float4 per row), rsub = tid>>1 -> row stripe of 128.
//   Per row each thread issues 8 independent table gathers; the 4-iteration
//   body is guard-free and fully unrolled so the compiler batches loads
//   across iterations (up to 32 gathers in flight).
//   Codebook slice (16ch x 256 f32 = 16KB) staged in LDS -> 8 blocks/CU.
// ---------------------------------------------------------------------------
template <typename TabT>
__global__ __launch_bounds__(256) void gather_kernel(
    const v4i* __restrict__ left, const v4i* __restrict__ right,
    const TabT* __restrict__ tab, const float* __restrict__ cb,
    v4f* __restrict__ out) {
  __shared__ float cbs[CPG * KK];  // 16 KB

  const int g     = blockIdx.x & (GROUPS - 1);
  const int chunk = blockIdx.x >> 4;
  const int q     = threadIdx.x & 1;   // channel octet within group
  const int rsub  = threadIdx.x >> 1;  // 0..127

  // Stage this group's codebook slice into LDS (4096 floats = 1024 float4).
  {
    const v4f* cbg = (const v4f*)(cb + (size_t)(g * CPG) * KK);
    v4f* cbl = (v4f*)cbs;
#pragma unroll
    for (int i = 0; i < 4; ++i) cbl[threadIdx.x + i * 256] = cbg[threadIdx.x + i * 256];
  }
  __syncthreads();

  const int cbase = g * CPG + q * 8;                // first of 8 channels
  const TabT* t0 = tab + (size_t)cbase * (KK * KK);
  const float* cbq = cbs + (q * 8) * KK;
  const int vecoff = g * 4 + q * 2;                 // int4 offset in 64-int4 row

  int row = chunk * ROWS_PER_BLOCK + rsub;
#pragma unroll
  for (int it = 0; it < ROWS_PER_BLOCK / 128; ++it, row += 128) {
    size_t vi = (size_t)row * 64 + vecoff;
    v4i L0 = __builtin_nontemporal_load(&left[vi]);
    v4i L1 = __builtin_nontemporal_load(&left[vi + 1]);
    v4i R0 = __builtin_nontemporal_load(&right[vi]);
    v4i R1 = __builtin_nontemporal_load(&right[vi + 1]);

    unsigned i0 = (unsigned)(L0.x * KK + R0.x);
    unsigned i1 = (unsigned)(L0.y * KK + R0.y);
    unsigned i2 = (unsigned)(L0.z * KK + R0.z);
    unsigned i3 = (unsigned)(L0.w * KK + R0.w);
    unsigned i4 = (unsigned)(L1.x * KK + R1.x);
    unsigned i5 = (unsigned)(L1.y * KK + R1.y);
    unsigned i6 = (unsigned)(L1.z * KK + R1.z);
    unsigned i7 = (unsigned)(L1.w * KK + R1.w);

    unsigned c0 = (unsigned)t0[0u * 65536u + i0];
    unsigned c1 = (unsigned)t0[1u * 65536u + i1];
    unsigned c2 = (unsigned)t0[2u * 65536u + i2];
    unsigned c3 = (unsigned)t0[3u * 65536u + i3];
    unsigned c4 = (unsigned)t0[4u * 65536u + i4];
    unsigned c5 = (unsigned)t0[5u * 65536u + i5];
    unsigned c6 = (unsigned)t0[6u * 65536u + i6];
    unsigned c7 = (unsigned)t0[7u * 65536u + i7];

    v4f o0, o1;
    o0.x = cbq[0 * KK + c0];
    o0.y = cbq[1 * KK + c1];
    o0.z = cbq[2 * KK + c2];
    o0.w = cbq[3 * KK + c3];
    o1.x = cbq[4 * KK + c4];
    o1.y = cbq[5 * KK + c5];
    o1.z = cbq[6 * KK + c6];
    o1.w = cbq[7 * KK + c7];
    __builtin_nontemporal_store(o0, &out[vi]);
    __builtin_nontemporal_store(o1, &out[vi + 1]);
  }
}

extern "C" void kernel_launch(void* const* d_in, const int* in_sizes, int n_in,
                              void* d_out, int out_size, void* d_ws, size_t ws_size,
                              hipStream_t stream) {
  const int*   left  = (const int*)d_in[0];
  const int*   right = (const int*)d_in[1];
  const int*   wt    = (const int*)d_in[2];   // [C, K, K] int32
  const float* cb    = (const float*)d_in[3]; // [C, K] float32
  float* out = (float*)d_out;

  const int nrows = in_sizes[0] / CCH;        // 262144
  const int tab_elems = CCH * KK * KK;        // 16,777,216
  const int blocks = (nrows / ROWS_PER_BLOCK) * GROUPS;  // 8192

  if (ws_size >= (size_t)tab_elems) {
    unsigned char* tab8 = (unsigned char*)d_ws;
    int n4 = tab_elems / 4;
    compress_table_kernel<<<n4 / 256, 256, 0, stream>>>(
        (const int4*)wt, (uchar4*)tab8, n4);
    gather_kernel<unsigned char><<<blocks, 256, 0, stream>>>(
        (const v4i*)left, (const v4i*)right, tab8, cb, (v4f*)out);
  } else {
    // Fallback: gather directly from the int32 table (slower, always correct).
    gather_kernel<int><<<blocks, 256, 0, stream>>>(
        (const v4i*)left, (const v4i*)right, wt, cb, (v4f*)out);
  }
}